// Round 7
// baseline (69.987 us; speedup 1.0000x reference)
//
#include <hip/hip_runtime.h>
#include <math.h>

#define SLEN 4096
#define DH   64
#define BHN  64
#define CH   16
#define ROWSPER 256   // SLEN / CH

typedef float  f32x4   __attribute__((ext_vector_type(4)));
typedef float  f32x16  __attribute__((ext_vector_type(16)));
typedef short  s16x4   __attribute__((ext_vector_type(4)));
typedef __bf16 bf16x8  __attribute__((ext_vector_type(8)));

static constexpr float ANG = 3.8349519697141029e-4f;   // (pi/2)/4096

static __device__ __forceinline__ float featf(float x) {
    return x < 0.f ? __expf(x) : x + 1.f;   // elu+1 feature map
}
static __device__ __forceinline__ float b2f(short s) {
    unsigned u = ((unsigned)(unsigned short)s) << 16;
    float f; __builtin_memcpy(&f, &u, 4); return f;
}
static __device__ __forceinline__ short f2b(float f) {
    __bf16 h = (__bf16)f; short s; __builtin_memcpy(&s, &h, 2); return s;
}

#define GLD(SRC, DST) __builtin_amdgcn_global_load_lds(                        \
    (const __attribute__((address_space(1))) void*)(SRC),                      \
    (__attribute__((address_space(3))) void*)(DST), 16, 0, 0)

// ---------------- Kernel 1: partial KV aggregation ---------------------------
// 256-thread blocks (4 waves), 4-deep LDS ring of 16-row fp32 k/v tiles staged
// via global_load_lds(16B). Counted vmcnt + raw s_barrier (T3+T4).
// RACE FIX (R6->R7): STAGE is issued AFTER the step barrier, so the ring
// buffer being overwritten ((T+3)&3 == (T-1)&3) has been fully consumed by
// all waves (they passed this barrier only after finishing step T-1 reads).
// part: [bh*CH+ch][2(cos,sin)][64 d][64 e] bf16
__global__ __launch_bounds__(256) void kv_partial(const float* __restrict__ k,
                                                  const float* __restrict__ v,
                                                  short* __restrict__ part)
{
    static constexpr float CJ[8] = {
        1.0f, 0.999999926470f, 0.9999997058633f, 0.9999993381923f,
        0.9999988234532f, 0.9999981616455f, 0.9999973527695f, 0.9999963968250f};
    static constexpr float SJ[8] = {
        0.0f, 3.83495188e-4f, 7.66990319e-4f, 1.15048534e-3f,
        1.53398019e-3f, 1.91747481e-3f, 2.30096915e-3f, 2.68446316e-3f};
    static constexpr float RC16 = 0.99998117528260111f;   // cos(16*ANG)
    static constexpr float RS16 = 6.1358846491544753e-3f; // sin(16*ANG)

    __shared__ float kbuf[4][16][64];   // 4-deep ring, 4KB per tile
    __shared__ float vbuf[4][16][64];

    const int bx = blockIdx.x;
    const int bh = bx >> 4, ch = bx & 15;
    const size_t base = (size_t)bh * SLEN * DH;
    const int tid = threadIdx.x;
    const int w  = tid >> 6;          // wave 0..3
    const int l  = tid & 63;
    const int m  = l & 31;
    const int g  = l >> 5;            // 0/1
    const int dh = w >> 1;            // d half
    const int eh = w & 1;             // e half
    const int s_base = ch * ROWSPER;

    // angle for s = s_base + step*16 + g*8 (+j via CJ/SJ); rotate per step
    float c0, s0;
    __sincosf(ANG * (float)(s_base + g * 8), &s0, &c0);

    f32x16 accC = {}; f32x16 accS = {};

    // wave w stages rows [w*4, w*4+4) of each 16-row tile (1KB k + 1KB v)
#define STAGE(TILE, BUF) do {                                                  \
        const size_t r_ = base + (size_t)(s_base + (TILE) * 16 + w * 4) * DH + l * 4; \
        GLD(k + r_, &kbuf[BUF][w * 4][0]);                                     \
        GLD(v + r_, &vbuf[BUF][w * 4][0]);                                     \
    } while (0)

#define VMW(N) asm volatile("s_waitcnt vmcnt(" #N ")" ::: "memory")

#define STEP(T, NW) do {                                                       \
        VMW(NW);                           /* own tile-T loads landed */       \
        __builtin_amdgcn_s_barrier();      /* => whole tile T in LDS; all  */  \
        __builtin_amdgcn_sched_barrier(0); /* waves done reading tile T-1 */   \
        if ((T) + 3 < 16) STAGE((T) + 3, ((T) + 3) & 3);                       \
        const int buf_ = (T) & 3;                                              \
        float kf_[8], vf_[8];                                                  \
        _Pragma("unroll")                                                      \
        for (int j = 0; j < 8; ++j) {                                          \
            kf_[j] = kbuf[buf_][g * 8 + j][dh * 32 + m];                       \
            vf_[j] = vbuf[buf_][g * 8 + j][eh * 32 + m];                       \
        }                                                                      \
        union { bf16x8 vv; __bf16 e[8]; } Ac_, As_, Bv_;                       \
        _Pragma("unroll")                                                      \
        for (int j = 0; j < 8; ++j) {                                          \
            const float cj_ = c0 * CJ[j] - s0 * SJ[j];                         \
            const float sj_ = s0 * CJ[j] + c0 * SJ[j];                         \
            const float f_  = featf(kf_[j]);                                   \
            Ac_.e[j] = (__bf16)(f_ * cj_);                                     \
            As_.e[j] = (__bf16)(f_ * sj_);                                     \
            Bv_.e[j] = (__bf16)vf_[j];                                         \
        }                                                                      \
        accC = __builtin_amdgcn_mfma_f32_32x32x16_bf16(Ac_.vv, Bv_.vv, accC, 0, 0, 0); \
        accS = __builtin_amdgcn_mfma_f32_32x32x16_bf16(As_.vv, Bv_.vv, accS, 0, 0, 0); \
        { const float cn_ = c0 * RC16 - s0 * RS16;                             \
          s0 = s0 * RC16 + c0 * RS16; c0 = cn_; }                              \
    } while (0)

    STAGE(0, 0); STAGE(1, 1); STAGE(2, 2);   // 6 loads in flight per wave

    STEP(0, 4);  STEP(1, 4);  STEP(2, 4);  STEP(3, 4);
    STEP(4, 4);  STEP(5, 4);  STEP(6, 4);  STEP(7, 4);
    STEP(8, 4);  STEP(9, 4);  STEP(10, 4); STEP(11, 4);
    STEP(12, 4); STEP(13, 4); STEP(14, 2); STEP(15, 0);

#undef STEP
#undef VMW
#undef STAGE

    // C/D 32x32: col = lane&31, row = (reg&3) + 8*(reg>>2) + 4*(lane>>5)
    const size_t pb = (size_t)bx * 8192;
    #pragma unroll
    for (int r = 0; r < 16; ++r) {
        const int drow = dh * 32 + (r & 3) + 8 * (r >> 2) + 4 * g;
        const size_t o = pb + (size_t)drow * 64 + eh * 32 + m;
        part[o]        = f2b(accC[r]);
        part[o + 4096] = f2b(accS[r]);
    }
}

// ---------------- Kernel 2: reduce chunks, emit bf16 KV^T -------------------
// kvT layout: [bh][2(cos,sin)][64 e][64 d] bf16
__global__ __launch_bounds__(256) void kv_reduce(const short* __restrict__ part,
                                                 short* __restrict__ kvT)
{
    const int bx = blockIdx.x;          // 512 blocks: bh = bx>>3, seg = bx&7
    const int bh = bx >> 3, seg = bx & 7;
    const size_t pbase = (size_t)bh * CH * 8192;
    const int j0 = seg * 1024 + threadIdx.x * 4;
    float acc[4] = {};
    #pragma unroll
    for (int c = 0; c < CH; ++c) {
        const s16x4 sv = *(const s16x4*)&part[pbase + (size_t)c * 8192 + j0];
        #pragma unroll
        for (int i = 0; i < 4; ++i) acc[i] += b2f(sv[i]);
    }
    const int cs = j0 >> 12;
    const int d  = (j0 >> 6) & 63;
    const int e0 = j0 & 63;
    #pragma unroll
    for (int i = 0; i < 4; ++i)
        kvT[(size_t)bh * 8192 + cs * 4096 + (e0 + i) * 64 + d] = f2b(acc[i]);
}

// ---------------- Kernel 3: out = Qc*KVc + Qs*KVs (MFMA) --------------------
__global__ __launch_bounds__(256) void out_kernel(const float* __restrict__ q,
                                                  const short* __restrict__ kvT,
                                                  float* __restrict__ out)
{
    const int bx = blockIdx.x;
    const int bh = bx >> 4, chunk = bx & 15;
    const int t = threadIdx.x;
    const int wv = t >> 6, ln = t & 63, m = ln & 15, g = ln >> 4;
    const size_t qbase = (size_t)bh * SLEN * DH;
    const size_t kvb   = (size_t)bh * 8192;

    bf16x8 Bc[4][2], Bs[4][2];
    #pragma unroll
    for (int nt = 0; nt < 4; ++nt)
        #pragma unroll
        for (int b = 0; b < 2; ++b) {
            const int off = (nt * 16 + m) * 64 + b * 32 + g * 8;
            Bc[nt][b] = *(const bf16x8*)&kvT[kvb + off];
            Bs[nt][b] = *(const bf16x8*)&kvT[kvb + 4096 + off];
        }

    const int sA = chunk * 256 + wv * 16 + m;
    f32x4 qb[4], qn[4];
    #pragma unroll
    for (int p = 0; p < 4; ++p)
        qb[p] = *(const f32x4*)&q[qbase + (size_t)sA * DH + (p >> 1) * 32 + g * 8 + (p & 1) * 4];

    for (int it = 0; it < 4; ++it) {
        const int srow = sA + it * 64;
        if (it < 3) {
            #pragma unroll
            for (int p = 0; p < 4; ++p)
                qn[p] = *(const f32x4*)&q[qbase + (size_t)(srow + 64) * DH + (p >> 1) * 32 + g * 8 + (p & 1) * 4];
        }
        float sn, c;
        __sincosf(ANG * (float)srow, &sn, &c);
        union { bf16x8 v; __bf16 e[8]; } Ac[2], As[2];
        #pragma unroll
        for (int p = 0; p < 4; ++p) {
            #pragma unroll
            for (int i = 0; i < 4; ++i) {
                const float qf = featf(qb[p][i]);
                Ac[p >> 1].e[(p & 1) * 4 + i] = (__bf16)(qf * c);
                As[p >> 1].e[(p & 1) * 4 + i] = (__bf16)(qf * sn);
            }
        }
        f32x4 acc[4] = {};
        #pragma unroll
        for (int nt = 0; nt < 4; ++nt) {
            acc[nt] = __builtin_amdgcn_mfma_f32_16x16x32_bf16(Ac[0].v, Bc[nt][0], acc[nt], 0, 0, 0);
            acc[nt] = __builtin_amdgcn_mfma_f32_16x16x32_bf16(Ac[1].v, Bc[nt][1], acc[nt], 0, 0, 0);
            acc[nt] = __builtin_amdgcn_mfma_f32_16x16x32_bf16(As[0].v, Bs[nt][0], acc[nt], 0, 0, 0);
            acc[nt] = __builtin_amdgcn_mfma_f32_16x16x32_bf16(As[1].v, Bs[nt][1], acc[nt], 0, 0, 0);
        }
        const int s0 = chunk * 256 + (it * 4 + wv) * 16;
        #pragma unroll
        for (int r = 0; r < 4; ++r) {
            const size_t ob = ((size_t)bh * SLEN + s0 + g * 4 + r) * 64;
            #pragma unroll
            for (int nt = 0; nt < 4; ++nt)
                out[ob + nt * 16 + m] = acc[nt][r];
        }
        if (it < 3) {
            #pragma unroll
            for (int p = 0; p < 4; ++p) qb[p] = qn[p];
        }
    }
}

extern "C" void kernel_launch(void* const* d_in, const int* in_sizes, int n_in,
                              void* d_out, int out_size, void* d_ws, size_t ws_size,
                              hipStream_t stream) {
    const float* q = (const float*)d_in[0];
    const float* k = (const float*)d_in[1];
    const float* v = (const float*)d_in[2];
    float* out  = (float*)d_out;
    short* part = (short*)d_ws;                                        // 16 MB
    short* kvT  = (short*)((char*)d_ws + (size_t)BHN * CH * 8192 * 2); // +1 MB

    hipLaunchKernelGGL(kv_partial, dim3(BHN * CH), dim3(256), 0, stream, k, v, part);
    hipLaunchKernelGGL(kv_reduce,  dim3(BHN * 8),  dim3(256), 0, stream, part, kvT);
    hipLaunchKernelGGL(out_kernel, dim3(BHN * 16), dim3(256), 0, stream, q, kvT, out);
}

// Round 8
// 68.516 us; speedup vs baseline: 1.0215x; 1.0215x over previous
//
#include <hip/hip_runtime.h>
#include <math.h>

#define SLEN 4096
#define DH   64
#define BHN  64
#define CH   16
#define ROWSPER 256   // SLEN / CH
#define TROWS 32      // rows per staged tile
#define NTILES 8      // ROWSPER / TROWS

typedef float  f32x4   __attribute__((ext_vector_type(4)));
typedef float  f32x16  __attribute__((ext_vector_type(16)));
typedef short  s16x4   __attribute__((ext_vector_type(4)));
typedef __bf16 bf16x8  __attribute__((ext_vector_type(8)));

static constexpr float ANG = 3.8349519697141029e-4f;   // (pi/2)/4096

static __device__ __forceinline__ float featf(float x) {
    return x < 0.f ? __expf(x) : x + 1.f;   // elu+1 feature map
}
static __device__ __forceinline__ float b2f(short s) {
    unsigned u = ((unsigned)(unsigned short)s) << 16;
    float f; __builtin_memcpy(&f, &u, 4); return f;
}
static __device__ __forceinline__ short f2b(float f) {
    __bf16 h = (__bf16)f; short s; __builtin_memcpy(&s, &h, 2); return s;
}

#define GLD(SRC, DST) __builtin_amdgcn_global_load_lds(                        \
    (const __attribute__((address_space(1))) void*)(SRC),                      \
    (__attribute__((address_space(3))) void*)(DST), 16, 0, 0)

// ---------------- Kernel 1: partial KV aggregation ---------------------------
// m97-style 2-barrier streaming loop: 32-row fp32 k/v tiles (16 KB/step)
// double-buffered in LDS, staged with global_load_lds(16B). __syncthreads'
// implicit vmcnt(0) drain makes it race-free; the drain (~900cy) is small vs
// the ~2.6us/step per-CU memory budget. Wave w computes quadrant (dh,eh),
// 4x mfma 32x32x16 per step.  part: [bh*CH+ch][2(cos,sin)][64 d][64 e] bf16
__global__ __launch_bounds__(256) void kv_partial(const float* __restrict__ k,
                                                  const float* __restrict__ v,
                                                  short* __restrict__ part)
{
    static constexpr float CJ[8] = {
        1.0f, 0.999999926470f, 0.9999997058633f, 0.9999993381923f,
        0.9999988234532f, 0.9999981616455f, 0.9999973527695f, 0.9999963968250f};
    static constexpr float SJ[8] = {
        0.0f, 3.83495188e-4f, 7.66990319e-4f, 1.15048534e-3f,
        1.53398019e-3f, 1.91747481e-3f, 2.30096915e-3f, 2.68446316e-3f};
    static constexpr float RC16 = 0.99998117528260111f;   // cos(16*ANG)
    static constexpr float RS16 = 6.1358846491544753e-3f; // sin(16*ANG)

    __shared__ float kbuf[2][TROWS][64];   // 8 KB per buffer
    __shared__ float vbuf[2][TROWS][64];

    const int bx = blockIdx.x;
    const int bh = bx >> 4, ch = bx & 15;
    const size_t base = (size_t)bh * SLEN * DH;
    const int tid = threadIdx.x;
    const int w  = tid >> 6;          // wave 0..3
    const int l  = tid & 63;
    const int m  = l & 31;
    const int g  = l >> 5;            // 0/1
    const int dh = w >> 1;            // d half
    const int eh = w & 1;             // e half
    const int s_base = ch * ROWSPER;

    // theta = ANG*(s_base + t*32 + ks*16 + g*8); rotate by 16*ANG per chunk
    float c0, s0;
    __sincosf(ANG * (float)(s_base + g * 8), &s0, &c0);

    f32x16 accC = {}; f32x16 accS = {};

    // wave w stages rows [w*8, w*8+8) of the 32-row tile: 2 GLD k + 2 GLD v
#define STAGE(TILE, BUF) do {                                                  \
        _Pragma("unroll")                                                      \
        for (int i_ = 0; i_ < 2; ++i_) {                                       \
            const size_t r_ = base +                                           \
                (size_t)(s_base + (TILE) * TROWS + w * 8 + i_ * 4) * DH + l * 4; \
            GLD(k + r_, &kbuf[BUF][w * 8 + i_ * 4][0]);                        \
            GLD(v + r_, &vbuf[BUF][w * 8 + i_ * 4][0]);                        \
        } } while (0)

    STAGE(0, 0);
    __syncthreads();                       // tile 0 resident

    #pragma unroll
    for (int t = 0; t < NTILES; ++t) {
        const int buf = t & 1;
        if (t + 1 < NTILES) STAGE(t + 1, buf ^ 1);   // overlaps with compute

        #pragma unroll
        for (int ks = 0; ks < 2; ++ks) {             // two K=16 chunks
            float kf_[8], vf_[8];
            #pragma unroll
            for (int j = 0; j < 8; ++j) {
                const int r = ks * 16 + g * 8 + j;
                kf_[j] = kbuf[buf][r][dh * 32 + m];
                vf_[j] = vbuf[buf][r][eh * 32 + m];
            }
            union { bf16x8 vv; __bf16 e[8]; } Ac_, As_, Bv_;
            #pragma unroll
            for (int j = 0; j < 8; ++j) {
                const float cj_ = c0 * CJ[j] - s0 * SJ[j];
                const float sj_ = s0 * CJ[j] + c0 * SJ[j];
                const float f_  = featf(kf_[j]);
                Ac_.e[j] = (__bf16)(f_ * cj_);
                As_.e[j] = (__bf16)(f_ * sj_);
                Bv_.e[j] = (__bf16)vf_[j];
            }
            accC = __builtin_amdgcn_mfma_f32_32x32x16_bf16(Ac_.vv, Bv_.vv, accC, 0, 0, 0);
            accS = __builtin_amdgcn_mfma_f32_32x32x16_bf16(As_.vv, Bv_.vv, accS, 0, 0, 0);
            const float cn_ = c0 * RC16 - s0 * RS16;     // advance 16 rows
            s0 = s0 * RC16 + c0 * RS16; c0 = cn_;
        }
        __syncthreads();   // all reads of buf done + tile t+1 landed (vmcnt drain)
    }
#undef STAGE

    // C/D 32x32: col = lane&31, row = (reg&3) + 8*(reg>>2) + 4*(lane>>5)
    const size_t pb = (size_t)bx * 8192;
    #pragma unroll
    for (int r = 0; r < 16; ++r) {
        const int drow = dh * 32 + (r & 3) + 8 * (r >> 2) + 4 * g;
        const size_t o = pb + (size_t)drow * 64 + eh * 32 + m;
        part[o]        = f2b(accC[r]);
        part[o + 4096] = f2b(accS[r]);
    }
}

// ---------------- Kernel 2: reduce chunks, emit bf16 KV^T -------------------
// kvT layout: [bh][2(cos,sin)][64 e][64 d] bf16
__global__ __launch_bounds__(256) void kv_reduce(const short* __restrict__ part,
                                                 short* __restrict__ kvT)
{
    const int bx = blockIdx.x;          // 512 blocks: bh = bx>>3, seg = bx&7
    const int bh = bx >> 3, seg = bx & 7;
    const size_t pbase = (size_t)bh * CH * 8192;
    const int j0 = seg * 1024 + threadIdx.x * 4;
    float acc[4] = {};
    #pragma unroll
    for (int c = 0; c < CH; ++c) {
        const s16x4 sv = *(const s16x4*)&part[pbase + (size_t)c * 8192 + j0];
        #pragma unroll
        for (int i = 0; i < 4; ++i) acc[i] += b2f(sv[i]);
    }
    const int cs = j0 >> 12;
    const int d  = (j0 >> 6) & 63;
    const int e0 = j0 & 63;
    #pragma unroll
    for (int i = 0; i < 4; ++i)
        kvT[(size_t)bh * 8192 + cs * 4096 + (e0 + i) * 64 + d] = f2b(acc[i]);
}

// ---------------- Kernel 3: out = Qc*KVc + Qs*KVs (MFMA) --------------------
__global__ __launch_bounds__(256) void out_kernel(const float* __restrict__ q,
                                                  const short* __restrict__ kvT,
                                                  float* __restrict__ out)
{
    const int bx = blockIdx.x;
    const int bh = bx >> 4, chunk = bx & 15;
    const int t = threadIdx.x;
    const int wv = t >> 6, ln = t & 63, m = ln & 15, g = ln >> 4;
    const size_t qbase = (size_t)bh * SLEN * DH;
    const size_t kvb   = (size_t)bh * 8192;

    bf16x8 Bc[4][2], Bs[4][2];
    #pragma unroll
    for (int nt = 0; nt < 4; ++nt)
        #pragma unroll
        for (int b = 0; b < 2; ++b) {
            const int off = (nt * 16 + m) * 64 + b * 32 + g * 8;
            Bc[nt][b] = *(const bf16x8*)&kvT[kvb + off];
            Bs[nt][b] = *(const bf16x8*)&kvT[kvb + 4096 + off];
        }

    const int sA = chunk * 256 + wv * 16 + m;
    f32x4 qb[4], qn[4];
    #pragma unroll
    for (int p = 0; p < 4; ++p)
        qb[p] = *(const f32x4*)&q[qbase + (size_t)sA * DH + (p >> 1) * 32 + g * 8 + (p & 1) * 4];

    for (int it = 0; it < 4; ++it) {
        const int srow = sA + it * 64;
        if (it < 3) {
            #pragma unroll
            for (int p = 0; p < 4; ++p)
                qn[p] = *(const f32x4*)&q[qbase + (size_t)(srow + 64) * DH + (p >> 1) * 32 + g * 8 + (p & 1) * 4];
        }
        float sn, c;
        __sincosf(ANG * (float)srow, &sn, &c);
        union { bf16x8 v; __bf16 e[8]; } Ac[2], As[2];
        #pragma unroll
        for (int p = 0; p < 4; ++p) {
            #pragma unroll
            for (int i = 0; i < 4; ++i) {
                const float qf = featf(qb[p][i]);
                Ac[p >> 1].e[(p & 1) * 4 + i] = (__bf16)(qf * c);
                As[p >> 1].e[(p & 1) * 4 + i] = (__bf16)(qf * sn);
            }
        }
        f32x4 acc[4] = {};
        #pragma unroll
        for (int nt = 0; nt < 4; ++nt) {
            acc[nt] = __builtin_amdgcn_mfma_f32_16x16x32_bf16(Ac[0].v, Bc[nt][0], acc[nt], 0, 0, 0);
            acc[nt] = __builtin_amdgcn_mfma_f32_16x16x32_bf16(Ac[1].v, Bc[nt][1], acc[nt], 0, 0, 0);
            acc[nt] = __builtin_amdgcn_mfma_f32_16x16x32_bf16(As[0].v, Bs[nt][0], acc[nt], 0, 0, 0);
            acc[nt] = __builtin_amdgcn_mfma_f32_16x16x32_bf16(As[1].v, Bs[nt][1], acc[nt], 0, 0, 0);
        }
        const int s0 = chunk * 256 + (it * 4 + wv) * 16;
        #pragma unroll
        for (int r = 0; r < 4; ++r) {
            const size_t ob = ((size_t)bh * SLEN + s0 + g * 4 + r) * 64;
            #pragma unroll
            for (int nt = 0; nt < 4; ++nt)
                out[ob + nt * 16 + m] = acc[nt][r];
        }
        if (it < 3) {
            #pragma unroll
            for (int p = 0; p < 4; ++p) qb[p] = qn[p];
        }
    }
}

extern "C" void kernel_launch(void* const* d_in, const int* in_sizes, int n_in,
                              void* d_out, int out_size, void* d_ws, size_t ws_size,
                              hipStream_t stream) {
    const float* q = (const float*)d_in[0];
    const float* k = (const float*)d_in[1];
    const float* v = (const float*)d_in[2];
    float* out  = (float*)d_out;
    short* part = (short*)d_ws;                                        // 16 MB
    short* kvT  = (short*)((char*)d_ws + (size_t)BHN * CH * 8192 * 2); // +1 MB

    hipLaunchKernelGGL(kv_partial, dim3(BHN * CH), dim3(256), 0, stream, k, v, part);
    hipLaunchKernelGGL(kv_reduce,  dim3(BHN * 8),  dim3(256), 0, stream, part, kvT);
    hipLaunchKernelGGL(out_kernel, dim3(BHN * 16), dim3(256), 0, stream, q, kvT, out);
}